// Round 8
// baseline (220.674 us; speedup 1.0000x reference)
//
#include <hip/hip_runtime.h>
#include <math.h>

#define T_    1024
#define B_    8
#define D_    256
#define H_    16
#define HD_   16
#define DFF_  2048
#define NODES_ 81
#define INDIM_ 162
#define E_    648
#define M_    (T_*B_)   // 8192 rows (t*B+b)

typedef __bf16 bf16x8 __attribute__((ext_vector_type(8)));
typedef float  f32x4  __attribute__((ext_vector_type(4)));
typedef unsigned short ushort_t;
typedef unsigned int   uint_t;

union bfpack { bf16x8 v; uint_t u[4]; };

__device__ __forceinline__ ushort_t f2bf(float f) {
    union { float f; uint_t u; } c; c.f = f;
    uint_t u = c.u;
    uint_t r = u + 0x7fffu + ((u >> 16) & 1u);
    return (ushort_t)(r >> 16);
}

__device__ __forceinline__ uint_t fbits(float f) {
    union { float f; uint_t u; } c; c.f = f;
    return c.u;
}

__device__ __forceinline__ bf16x8 zero8() {
    bf16x8 v;
#pragma unroll
    for (int e = 0; e < 8; e++) v[e] = (__bf16)0.0f;
    return v;
}

__device__ __forceinline__ void gload_lds16(const void* g, void* l) {
    __builtin_amdgcn_global_load_lds(
        (const __attribute__((address_space(1))) void*)g,
        (__attribute__((address_space(3))) void*)l, 16, 0, 0);
}

// ---------------------------------------------------------------------------
// One prep kernel: GCN-fold (A_hat in LDS) | 7 weight transposes | qkv bias |
// src->bf16 (batched, coalesced). Branch on blockIdx.x (block-uniform).
// grid 1555 x 256.
// ---------------------------------------------------------------------------
__device__ __forceinline__ void trans_tile(
        const float* __restrict__ in, ushort_t* __restrict__ out,
        float (*tile)[33], int K, int N, int Kp, int bx, int by) {
    int k0 = bx * 32, n0 = by * 32;
    int tx = threadIdx.x & 31, ty = threadIdx.x >> 5;
#pragma unroll
    for (int i = 0; i < 4; i++) {
        int r = k0 + ty + i * 8, c = n0 + tx;
        tile[ty + i * 8][tx] = (r < K && c < N) ? in[(size_t)r * N + c] : 0.f;
    }
    __syncthreads();
#pragma unroll
    for (int i = 0; i < 4; i++) {
        int r = n0 + ty + i * 8, c = k0 + tx;
        out[(size_t)r * Kp + c] = f2bf(tile[tx][ty + i * 8]);
    }
}

__global__ __launch_bounds__(256) void prep_all(
        const int* __restrict__ edge, const float* __restrict__ gcn_w,
        const float* __restrict__ gcn_b, const float* __restrict__ fc_w,
        const float* __restrict__ fc_b, const float* __restrict__ src,
        const float* __restrict__ wq, const float* __restrict__ wk,
        const float* __restrict__ wv, const float* __restrict__ wo,
        const float* __restrict__ dec_w, const float* __restrict__ w1,
        const float* __restrict__ w2,
        const float* __restrict__ bq, const float* __restrict__ bk,
        const float* __restrict__ bv,
        ushort_t* __restrict__ weffT, float* __restrict__ beff,
        ushort_t* __restrict__ srcb,
        ushort_t* __restrict__ wqkvT, ushort_t* __restrict__ woT,
        ushort_t* __restrict__ dwT, ushort_t* __restrict__ w1T,
        ushort_t* __restrict__ w2T, float* __restrict__ qkvbias) {
    __shared__ float A[NODES_ * NODES_];
    __shared__ float dinv[NODES_];
    __shared__ float tile[32][33];
    int bid = blockIdx.x;
    int tid = threadIdx.x;
    if (bid < 82) {
        for (int i = tid; i < NODES_ * NODES_; i += 256) A[i] = 0.f;
        __syncthreads();
        for (int e = tid; e < E_; e += 256) {
            int r = edge[e];
            int c = edge[E_ + e];
            atomicAdd(&A[c * NODES_ + r], 1.0f);
        }
        __syncthreads();
        if (tid < NODES_) A[tid * NODES_ + tid] += 1.0f;
        __syncthreads();
        if (tid < NODES_) {
            float s = 0.f;
            for (int k = 0; k < NODES_; k++) s += A[tid * NODES_ + k];
            dinv[tid] = (s > 0.f) ? rsqrtf(s) : 0.f;
        }
        __syncthreads();
        int d = tid, j = bid;
        if (j < NODES_) {
            float s0 = 0.f, s1 = 0.f;
            for (int i = 0; i < NODES_; i++) {
                float a = dinv[i] * A[i * NODES_ + j] * dinv[j];
                s0 += a * fc_w[(0 * NODES_ + i) * D_ + d];
                s1 += a * fc_w[(1 * NODES_ + i) * D_ + d];
            }
            weffT[d * 192 + j]          = f2bf(gcn_w[0] * s0 + gcn_w[1] * s1);
            weffT[d * 192 + NODES_ + j] = f2bf(gcn_w[2] * s0 + gcn_w[3] * s1);
        } else {
            float t0 = 0.f, t1 = 0.f;
            for (int i = 0; i < NODES_; i++) {
                t0 += fc_w[(0 * NODES_ + i) * D_ + d];
                t1 += fc_w[(1 * NODES_ + i) * D_ + d];
            }
            beff[d] = fc_b[d] + gcn_b[0] * t0 + gcn_b[1] * t1;
            for (int c = INDIM_; c < 192; c++) weffT[d * 192 + c] = 0;
        }
    } else if (bid < 1426) {
        int l = bid - 82;
        if (l < 64)        trans_tile(wq,    wqkvT,          tile, D_,   D_,     D_,   l & 7,  l >> 3);
        else if (l < 128)  trans_tile(wk,    wqkvT + 65536,  tile, D_,   D_,     D_,   (l-64) & 7,  (l-64) >> 3);
        else if (l < 192)  trans_tile(wv,    wqkvT + 131072, tile, D_,   D_,     D_,   (l-128) & 7, (l-128) >> 3);
        else if (l < 256)  trans_tile(wo,    woT,            tile, D_,   D_,     D_,   (l-192) & 7, (l-192) >> 3);
        else if (l < 320)  trans_tile(dec_w, dwT,            tile, D_,   INDIM_, D_,   (l-256) & 7, (l-256) >> 3);
        else if (l < 832)  trans_tile(w1,    w1T,            tile, D_,   DFF_,   D_,   (l-320) & 7, (l-320) >> 3);
        else               trans_tile(w2,    w2T,            tile, DFF_, D_,     DFF_, (l-832) & 63, (l-832) >> 6);
    } else if (bid == 1426) {
#pragma unroll
        for (int k = 0; k < 3; k++) {
            int i = k * 256 + tid;
            qkvbias[i] = (i < 256) ? bq[i] : ((i < 512) ? bk[i - 256] : bv[i - 512]);
        }
    } else {
        // src -> bf16 (padded to 192 cols): 128 blocks x 64 rows, coalesced.
        int blk = bid - 1427;               // 0..127
        size_t row0 = (size_t)blk * 64;
        const float* sp = src + row0 * INDIM_;
        ushort_t* dp = srcb + row0 * 192;
        for (int i = tid; i < 64 * INDIM_; i += 256) {
            int r = i / INDIM_;
            int c = i - r * INDIM_;
            dp[(size_t)r * 192 + c] = f2bf(sp[i]);
        }
        for (int i = tid; i < 64 * 30; i += 256) {
            int r = i / 30;
            int c = i - r * 30;
            dp[(size_t)r * 192 + INDIM_ + c] = 0;
        }
    }
}

// ---------------------------------------------------------------------------
// bf16 MFMA GEMM: C[M,N] = A[M,K] @ BT[N,K]^T + bias.
// TM=128: 128x128 tile, 4 waves x 64x64.  TM=64: 64x128, 4 waves x 64x32.
// TM=32: 32x128, 4 waves x 32x32 (grid doubles -> more blocks/CU, short-K).
// EP_QKV scales the q third by 0.25 (1/sqrt(HD), exact in bf16).
// ---------------------------------------------------------------------------
enum { EP_PE = 0, EP_QKV = 1, EP_PLAIN = 2, EP_RELU = 3, EP_DEC = 4, EP_PART = 5 };

template <int EPI, int TM, int KS>
__global__ __launch_bounds__(256) void gemm_bf16(
        const ushort_t* __restrict__ A, const ushort_t* __restrict__ BT,
        const float* __restrict__ bias, float* __restrict__ Cf,
        ushort_t* __restrict__ Cb, int M, int N, int K) {
    __shared__ ushort_t sA[TM * 64];
    __shared__ ushort_t sB[128 * 64];
    int tid = threadIdx.x;
    int w = tid >> 6, lane = tid & 63;
    int cc = lane & 15, q = lane >> 4;
    int bm = blockIdx.y * TM, bn = blockIdx.x * 128;
    int part = (KS > 1) ? blockIdx.z : 0;
    int kbeg = part * (K / KS), kend = kbeg + K / KS;

    int srow = (lane >> 3);
    int sslot = lane & 7;

    const int NI = (TM == 128) ? 4 : (TM / 16);
    const int NJ = (TM == 128) ? 4 : 2;
    int mbase = (TM == 128) ? ((w >> 1) * 64) : 0;
    int nbase = (TM == 128) ? ((w & 1) * 64) : (w * 32);

    f32x4 acc[NI][NJ];
#pragma unroll
    for (int i = 0; i < NI; i++)
#pragma unroll
        for (int j = 0; j < NJ; j++)
#pragma unroll
            for (int e = 0; e < 4; e++) acc[i][j][e] = 0.f;

    for (int k0 = kbeg; k0 < kend; k0 += 64) {
        if (TM == 128) {
#pragma unroll
            for (int i = 0; i < 4; i++) {
                int r = w * 32 + i * 8 + srow;
                const ushort_t* ga = A + (size_t)(bm + r) * K + k0 + ((sslot ^ (r & 7)) * 8);
                gload_lds16(ga, &sA[(w * 32 + i * 8) * 64]);
            }
        } else if (TM == 64) {
#pragma unroll
            for (int i = 0; i < 2; i++) {
                int r = w * 16 + i * 8 + srow;
                const ushort_t* ga = A + (size_t)(bm + r) * K + k0 + ((sslot ^ (r & 7)) * 8);
                gload_lds16(ga, &sA[(w * 16 + i * 8) * 64]);
            }
        } else {   // TM == 32
            int r = w * 8 + srow;
            const ushort_t* ga = A + (size_t)(bm + r) * K + k0 + ((sslot ^ (r & 7)) * 8);
            gload_lds16(ga, &sA[(w * 8) * 64]);
        }
#pragma unroll
        for (int i = 0; i < 4; i++) {
            int r = w * 32 + i * 8 + srow;
            const ushort_t* gb = BT + (size_t)(bn + r) * K + k0 + ((sslot ^ (r & 7)) * 8);
            gload_lds16(gb, &sB[(w * 32 + i * 8) * 64]);
        }
        __syncthreads();
#pragma unroll
        for (int ks = 0; ks < 2; ks++) {
            bf16x8 af[NI], bfr[NJ];
#pragma unroll
            for (int i = 0; i < NI; i++) {
                int m = mbase + i * 16 + cc;
                int off = m * 64 + (((ks * 4 + q) ^ (cc & 7)) * 8);
                af[i] = *(const bf16x8*)&sA[off];
            }
#pragma unroll
            for (int j = 0; j < NJ; j++) {
                int n = nbase + j * 16 + cc;
                int off = n * 64 + (((ks * 4 + q) ^ (cc & 7)) * 8);
                bfr[j] = *(const bf16x8*)&sB[off];
            }
#pragma unroll
            for (int i = 0; i < NI; i++)
#pragma unroll
                for (int j = 0; j < NJ; j++)
                    acc[i][j] = __builtin_amdgcn_mfma_f32_16x16x32_bf16(af[i], bfr[j], acc[i][j], 0, 0, 0);
        }
        __syncthreads();
    }

#pragma unroll
    for (int i = 0; i < NI; i++) {
#pragma unroll
        for (int j = 0; j < NJ; j++) {
            int col = bn + nbase + j * 16 + cc;
            float bv = 0.f;
            if (EPI == EP_DEC) bv = (col < INDIM_) ? bias[col] : 0.f;
            else if (EPI != EP_PART) bv = bias[col];
#pragma unroll
            for (int reg = 0; reg < 4; reg++) {
                int row = bm + mbase + i * 16 + q * 4 + reg;
                float v = acc[i][j][reg] + bv;
                if (EPI == EP_PE) {
                    int t = row >> 3;
                    float freq = __expf((float)(col & ~1) * (-9.210340371976184f / 256.f));
                    float ang = (float)t * freq;
                    v += (col & 1) ? __cosf(ang) : __sinf(ang);
                    Cf[(size_t)row * N + col] = v;
                    Cb[(size_t)row * N + col] = f2bf(v);
                } else if (EPI == EP_QKV) {
                    int t = row >> 3, b = row & 7;
                    int nn = col & 255, which = col >> 8;
                    int h = nn >> 4, hd = nn & 15;
                    float vq = (which == 0) ? v * 0.25f : v;   // fold 1/sqrt(HD) into q (exact)
                    Cb[(size_t)which * 2097152 +
                       ((size_t)((b * H_ + h) * T_ + t)) * HD_ + hd] = f2bf(vq);
                } else if (EPI == EP_PLAIN) {
                    Cf[(size_t)row * N + col] = v;
                } else if (EPI == EP_RELU) {
                    v = fmaxf(v, 0.f);
                    Cb[(size_t)row * N + col] = f2bf(v);
                } else if (EPI == EP_DEC) {
                    if (col < INDIM_) Cf[(size_t)row * INDIM_ + col] = v;
                } else if (EPI == EP_PART) {
                    Cf[(size_t)part * M * N + (size_t)row * N + col] = v;
                }
            }
        }
    }
}

// ---------------------------------------------------------------------------
// Fused GEMM + residual + LayerNorm (full row in one block, TN=256).
//   out = LN( X[row,:] + A[row,:]@BT^T + bias )  row-wise over 256 cols.
// 4 waves, wave w owns cols [w*64, w*64+64). TM=16 -> grid M/16=512 (2/CU:
// the occupancy regime R4 verified; R2's failure was TM=32 @ 1/CU).
// Row stats: per-lane partials -> shfl_xor over cc lanes -> LDS cross-wave.
// All stats fp32 from fp32 acc + fp32 residual.
// ---------------------------------------------------------------------------
template <int TM, bool WF32>
__global__ __launch_bounds__(256) void gemm_ln(
        const ushort_t* __restrict__ A, const ushort_t* __restrict__ BT,
        const float* __restrict__ bias, const float* __restrict__ X,
        const float* __restrict__ lw, const float* __restrict__ lb,
        float* __restrict__ outF, ushort_t* __restrict__ outB, int K) {
    const int NI = TM / 16;
    __shared__ ushort_t sA[TM * 64];
    __shared__ ushort_t sB[256 * 64];
    __shared__ float red[4][TM][2];
    int tid = threadIdx.x;
    int w = tid >> 6, lane = tid & 63;
    int cc = lane & 15, q = lane >> 4;
    int bm = blockIdx.x * TM;
    int srow = lane >> 3, sslot = lane & 7;
    int nbase = w * 64;

    f32x4 acc[NI][4];
#pragma unroll
    for (int i = 0; i < NI; i++)
#pragma unroll
        for (int j = 0; j < 4; j++)
#pragma unroll
            for (int e = 0; e < 4; e++) acc[i][j][e] = 0.f;

    for (int k0 = 0; k0 < K; k0 += 64) {
        // stage A: TM rows x 64 k
        if (TM == 64) {
#pragma unroll
            for (int i = 0; i < 2; i++) {
                int r = w * 16 + i * 8 + srow;
                const ushort_t* ga = A + (size_t)(bm + r) * K + k0 + ((sslot ^ (r & 7)) * 8);
                gload_lds16(ga, &sA[(w * 16 + i * 8) * 64]);
            }
        } else if (TM == 32) {
            int r = w * 8 + srow;
            const ushort_t* ga = A + (size_t)(bm + r) * K + k0 + ((sslot ^ (r & 7)) * 8);
            gload_lds16(ga, &sA[(w * 8) * 64]);
        } else {   // TM == 16: waves 0,1 stage 8 rows each
            if (w < 2) {
                int r = w * 8 + srow;
                const ushort_t* ga = A + (size_t)(bm + r) * K + k0 + ((sslot ^ (r & 7)) * 8);
                gload_lds16(ga, &sA[(w * 8) * 64]);
            }
        }
        // stage B: all 256 n-rows x 64 k
#pragma unroll
        for (int i = 0; i < 8; i++) {
            int r = w * 64 + i * 8 + srow;
            const ushort_t* gb = BT + (size_t)r * K + k0 + ((sslot ^ (r & 7)) * 8);
            gload_lds16(gb, &sB[(w * 64 + i * 8) * 64]);
        }
        __syncthreads();
#pragma unroll
        for (int ks = 0; ks < 2; ks++) {
            bf16x8 af[NI], bfr[4];
#pragma unroll
            for (int i = 0; i < NI; i++) {
                int m = i * 16 + cc;
                int off = m * 64 + (((ks * 4 + q) ^ (cc & 7)) * 8);
                af[i] = *(const bf16x8*)&sA[off];
            }
#pragma unroll
            for (int j = 0; j < 4; j++) {
                int n = nbase + j * 16 + cc;
                int off = n * 64 + (((ks * 4 + q) ^ (cc & 7)) * 8);
                bfr[j] = *(const bf16x8*)&sB[off];
            }
#pragma unroll
            for (int i = 0; i < NI; i++)
#pragma unroll
                for (int j = 0; j < 4; j++)
                    acc[i][j] = __builtin_amdgcn_mfma_f32_16x16x32_bf16(af[i], bfr[j], acc[i][j], 0, 0, 0);
        }
        __syncthreads();
    }

    // epilogue: v = acc + bias + residual; row-wise LN over 256 cols
    float s[NI][4], sq[NI][4];
#pragma unroll
    for (int i = 0; i < NI; i++)
#pragma unroll
        for (int reg = 0; reg < 4; reg++) { s[i][reg] = 0.f; sq[i][reg] = 0.f; }

#pragma unroll
    for (int i = 0; i < NI; i++)
#pragma unroll
        for (int j = 0; j < 4; j++) {
            int col = nbase + j * 16 + cc;
            float bv = bias[col];
#pragma unroll
            for (int reg = 0; reg < 4; reg++) {
                int row = bm + i * 16 + q * 4 + reg;
                float v = acc[i][j][reg] + bv + X[(size_t)row * D_ + col];
                acc[i][j][reg] = v;
                s[i][reg] += v;
                sq[i][reg] += v * v;
            }
        }
    // reduce across the 16 cc-lanes (same q => same rows)
#pragma unroll
    for (int i = 0; i < NI; i++)
#pragma unroll
        for (int reg = 0; reg < 4; reg++) {
            float a = s[i][reg], b2 = sq[i][reg];
#pragma unroll
            for (int off = 1; off < 16; off <<= 1) {
                a += __shfl_xor(a, off);
                b2 += __shfl_xor(b2, off);
            }
            s[i][reg] = a; sq[i][reg] = b2;
        }
    if (cc == 0) {
#pragma unroll
        for (int i = 0; i < NI; i++)
#pragma unroll
            for (int reg = 0; reg < 4; reg++) {
                int lr = i * 16 + q * 4 + reg;
                red[w][lr][0] = s[i][reg];
                red[w][lr][1] = sq[i][reg];
            }
    }
    __syncthreads();
#pragma unroll
    for (int i = 0; i < NI; i++)
#pragma unroll
        for (int reg = 0; reg < 4; reg++) {
            int lr = i * 16 + q * 4 + reg;
            float ts = red[0][lr][0] + red[1][lr][0] + red[2][lr][0] + red[3][lr][0];
            float tq = red[0][lr][1] + red[1][lr][1] + red[2][lr][1] + red[3][lr][1];
            float mean = ts * (1.f / 256.f);
            float var  = tq * (1.f / 256.f) - mean * mean;
            float rstd = rsqrtf(var + 1e-5f);
            int row = bm + lr;
#pragma unroll
            for (int j = 0; j < 4; j++) {
                int col = nbase + j * 16 + cc;
                float o = (acc[i][j][reg] - mean) * rstd * lw[col] + lb[col];
                if (WF32) outF[(size_t)row * D_ + col] = o;
                outB[(size_t)row * D_ + col] = f2bf(o);
            }
        }
}

// ---------------------------------------------------------------------------
// MFMA causal attention v7: UNSPLIT — one block per (qc,bh) does its full
// causal key range and writes normalized bf16 ctx directly (no partials, no
// reduce kernel). Long blocks (qc=7, 16 kb) dispatch first via qc=7-blockIdx.y.
// PV packed across j-subtile pairs (full K=32); l via per-lane VALU + shfl
// butterfly (xor 16,32 gives every lane the full row sum).
// ---------------------------------------------------------------------------
__global__ __launch_bounds__(256) void attn_mfma(
        const ushort_t* __restrict__ Qb, const ushort_t* __restrict__ Kb,
        const ushort_t* __restrict__ Vb, ushort_t* __restrict__ ctxb) {
    int bh = blockIdx.x;
    int qc = 7 - blockIdx.y;       // longest blocks first
    int tid = threadIdx.x;
    int w = tid >> 6, lane = tid & 63;
    int cc = lane & 15, q = lane >> 4;
    int qb0 = qc * 128;
    int kend = 2 * (qc + 1);

    __shared__ ushort_t VTs[2][16 * 72];   // [hd][key], stride 72

    const ushort_t* Qp = Qb + (size_t)bh * (T_ * HD_);
    const ushort_t* Kp = Kb + (size_t)bh * (T_ * HD_);
    const ushort_t* Vp = Vb + (size_t)bh * (T_ * HD_);

    // Q fragments (B-operand): B[n=qrow][k=q*8+e], valid k<16 -> q<2
    bf16x8 qf[2];
#pragma unroll
    for (int i = 0; i < 2; i++) {
        if (q < 2)
            qf[i] = *(const bf16x8*)&Qp[(size_t)(qb0 + w * 32 + i * 16 + cc) * HD_ + q * 8];
        else
            qf[i] = zero8();
    }

    f32x4 ot[2];
    float lsum[2];
#pragma unroll
    for (int i = 0; i < 2; i++) {
        lsum[i] = 0.f;
#pragma unroll
        for (int e = 0; e < 4; e++) ot[i][e] = 0.f;
    }

    int qmaxw = qb0 + w * 32 + 31;

    for (int kb = 0; kb < kend; kb++) {
        ushort_t* vbuf = VTs[kb & 1];
        {   // V^T staging across all 256 threads (4 b16 writes each)
            int r = tid >> 2, c0 = (tid & 3) * 4;
            ushort4 vv = *(const ushort4*)&Vp[(size_t)(kb * 64 + r) * HD_ + c0];
            vbuf[(c0 + 0) * 72 + r] = vv.x;
            vbuf[(c0 + 1) * 72 + r] = vv.y;
            vbuf[(c0 + 2) * 72 + r] = vv.z;
            vbuf[(c0 + 3) * 72 + r] = vv.w;
        }
        __syncthreads();
        if (kb * 64 > qmaxw) continue;

        // hoisted K fragments: 4 independent global loads
        bf16x8 kf[4];
#pragma unroll
        for (int j = 0; j < 4; j++) {
            if (q < 2)
                kf[j] = *(const bf16x8*)&Kp[(size_t)(kb * 64 + j * 16 + cc) * HD_ + q * 8];
            else
                kf[j] = zero8();
        }

        // S^T = K.Q^T (q pre-scaled)
        f32x4 s[2][4];
#pragma unroll
        for (int j = 0; j < 4; j++)
#pragma unroll
            for (int i = 0; i < 2; i++) {
                f32x4 z;
#pragma unroll
                for (int e = 0; e < 4; e++) z[e] = 0.f;
                s[i][j] = __builtin_amdgcn_mfma_f32_16x16x32_bf16(kf[j], qf[i], z, 0, 0, 0);
            }

        // exp + (diagonal-only) mask + pack pairs -> single full-K PV MFMA
#pragma unroll
        for (int jj = 0; jj < 2; jj++) {
            int j0 = jj * 2, j1 = j0 + 1;
            bfpack af;
            const uint_t* vt0 = (const uint_t*)&vbuf[cc * 72 + j0 * 16 + q * 4];
            const uint_t* vt1 = (const uint_t*)&vbuf[cc * 72 + j1 * 16 + q * 4];
            af.u[0] = vt0[0]; af.u[1] = vt0[1];
            af.u[2] = vt1[0]; af.u[3] = vt1[1];
            int key00 = kb * 64 + j0 * 16 + q * 4;
            int key01 = key00 + 16;
#pragma unroll
            for (int i = 0; i < 2; i++) {
                float p0 = __expf(s[i][j0][0]);
                float p1 = __expf(s[i][j0][1]);
                float p2 = __expf(s[i][j0][2]);
                float p3 = __expf(s[i][j0][3]);
                float p4 = __expf(s[i][j1][0]);
                float p5 = __expf(s[i][j1][1]);
                float p6 = __expf(s[i][j1][2]);
                float p7 = __expf(s[i][j1][3]);
                int qsub = qb0 + w * 32 + i * 16;
                if (kb * 64 + j0 * 16 + 15 > qsub) {  // wave-uniform
                    int qrow = qsub + cc;
                    if (key00 + 0 > qrow) p0 = 0.f;
                    if (key00 + 1 > qrow) p1 = 0.f;
                    if (key00 + 2 > qrow) p2 = 0.f;
                    if (key00 + 3 > qrow) p3 = 0.f;
                }
                if (kb * 64 + j1 * 16 + 15 > qsub) {  // wave-uniform
                    int qrow = qsub + cc;
                    if (key01 + 0 > qrow) p4 = 0.f;
                    if (key01 + 1 > qrow) p5 = 0.f;
                    if (key01 + 2 > qrow) p6 = 0.f;
                    if (key01 + 3 > qrow) p7 = 0.f;
                }
                bfpack pf;
                pf.u[0] = (fbits(p0) >> 16) | (fbits(p1) & 0xffff0000u);
                pf.u[1] = (fbits(p2) >> 16) | (fbits(p3) & 0xffff0000u);
                pf.u[2] = (fbits(p4) >> 16) | (fbits(p5) & 0xffff0000u);
                pf.u[3] = (fbits(p6) >> 16) | (fbits(p7) & 0xffff0000u);
                ot[i] = __builtin_amdgcn_mfma_f32_16x16x32_bf16(af.v, pf.v, ot[i], 0, 0, 0);
                lsum[i] += ((p0 + p1) + (p2 + p3)) + ((p4 + p5) + (p6 + p7));
            }
        }
    }

    // epilogue: lane (cc,q) holds O^T d=q*4+reg for qrow=...+cc. The xor(16)+
    // xor(32) butterfly leaves the FULL row-sum l in every lane of the
    // cc-group, so each lane normalizes its own 4 outputs and writes bf16 ctx
    // directly: ctx[t*B+b, h*16 + q*4 .. +3].
    int b = bh >> 4, h = bh & 15;
#pragma unroll
    for (int i = 0; i < 2; i++) {
        float l = lsum[i];
        l += __shfl_xor(l, 16);
        l += __shfl_xor(l, 32);
        float inv = 1.f / l;
        int t = qb0 + w * 32 + i * 16 + cc;
        ushort4 u;
        u.x = f2bf(ot[i][0] * inv);
        u.y = f2bf(ot[i][1] * inv);
        u.z = f2bf(ot[i][2] * inv);
        u.w = f2bf(ot[i][3] * inv);
        *(ushort4*)&ctxb[((size_t)t * B_ + b) * D_ + h * HD_ + q * 4] = u;
    }
}

// ---------------------------------------------------------------------------
extern "C" void kernel_launch(void* const* d_in, const int* in_sizes, int n_in,
                              void* d_out, int out_size, void* d_ws, size_t ws_size,
                              hipStream_t stream) {
    (void)in_sizes; (void)n_in; (void)out_size; (void)ws_size;
    const float* src     = (const float*)d_in[0];
    const int*   edge    = (const int*)d_in[1];
    const float* gcn_w   = (const float*)d_in[2];
    const float* gcn_b   = (const float*)d_in[3];
    const float* fc_w    = (const float*)d_in[4];
    const float* fc_b    = (const float*)d_in[5];
    const float* wq      = (const float*)d_in[6];
    const float* bq      = (const float*)d_in[7];
    const float* wk      = (const float*)d_in[8];
    const float* bk      = (const float*)d_in[9];
    const float* wv      = (const float*)d_in[10];
    const float* bv      = (const float*)d_in[11];
    const float* wo      = (const float*)d_in[12];
    const float* bo      = (const float*)d_in[13];
    const float* ln1_w   = (const float*)d_in[14];
    const float* ln1_b   = (const float*)d_in[15];
    const float* ffn_w1  = (const float*)d_in[16];
    const float* ffn_b1  = (const float*)d_in[17];
    const float* ffn_w2  = (const float*)d_in[18];
    const float* ffn_b2  = (const float*)d_in[19];
    const float* ln2_w   = (const float*)d_in[20];
    const float* ln2_b   = (const float*)d_in[21];
    const float* dec_w   = (const float*)d_in[22];
    const float* dec_b   = (const float*)d_in[23];
    float* out = (float*)d_out;

    float* ws = (float*)d_ws;
    // fp32 region
    float* beff    = ws;                      // 256
    float* qkvbias = ws + 256;                // 768
    float* x0      = ws + 1024;               // 2097152
    float* tmp     = x0  + 2097152;           // (unused slabs kept for layout)
    float* tmp2    = tmp + 2097152;
    float* x1      = tmp2 + 2097152;
    // bf16 region (float offset 10486784 -> 16B aligned)
    ushort_t* ub   = (ushort_t*)(ws + 10486784);
    ushort_t* srcb = ub;                      // 8192*192
    ushort_t* x0b  = ub + 1572864;            // 8192*256
    ushort_t* x1b  = x0b + 2097152;
    ushort_t* x2b  = x1b + 2097152;
    ushort_t* ctxb = x2b + 2097152;
    ushort_t* hb   = ctxb + 2097152;          // 8192*2048
    ushort_t* qkvb = hb + 16777216;           // 3 * 2097152
    ushort_t* weffT= qkvb + 6291456;          // 256*192
    ushort_t* wqkvT= weffT + 49152;           // 768*256
    ushort_t* woT  = wqkvT + 196608;          // 256*256
    ushort_t* w1T  = woT + 65536;             // 2048*256
    ushort_t* w2T  = w1T + 524288;            // 256*2048
    ushort_t* dwT  = w2T + 524288;            // 256*256 (rows 162..255 zero)
    (void)tmp; (void)tmp2;

    prep_all<<<1555, 256, 0, stream>>>(edge, gcn_w, gcn_b, fc_w, fc_b, src,
                                       wq, wk, wv, wo, dec_w, ffn_w1, ffn_w2,
                                       bq, bk, bv, weffT, beff, srcb,
                                       wqkvT, woT, dwT, w1T, w2T, qkvbias);

    // x0 = src @ W_eff + b_eff + PE   (fp32 + bf16), TM=32 -> 512 blocks
    gemm_bf16<EP_PE, 32, 1><<<dim3(2, 256), 256, 0, stream>>>(srcb, weffT, beff, x0, x0b, M_, D_, 192);
    // fused q|k|v -> bf16 [B*H,T,16] x3 (q pre-scaled by 0.25)
    gemm_bf16<EP_QKV, 64, 1><<<dim3(6, 128), 256, 0, stream>>>(x0b, wqkvT, qkvbias, nullptr, qkvb, M_, 768, D_);
    // causal attention: unsplit, writes ctx bf16 [8192,256] directly
    attn_mfma<<<dim3(128, 8), 256, 0, stream>>>(qkvb, qkvb + 2097152, qkvb + 4194304, ctxb);
    // x1 = LN(x0 + ctx @ wo + bo)   fused GEMM+LN, TM=16 -> 512 blocks (2/CU)
    gemm_ln<16, true><<<512, 256, 0, stream>>>(ctxb, woT, bo, x0, ln1_w, ln1_b, x1, x1b, D_);
    // h = relu(x1 @ w1 + b1)  (bf16), TM=64 -> 2048 blocks (occupancy lever)
    gemm_bf16<EP_RELU, 64, 1><<<dim3(16, 128), 256, 0, stream>>>(x1b, w1T, ffn_b1, nullptr, hb, M_, DFF_, D_);
    // x2 = LN(x1 + h @ w2 + b2)   fused GEMM+LN, TM=16 -> 512 blocks (2/CU),
    // K=2048 (no split-K partials, no ln2 dispatch; hb read exactly once)
    gemm_ln<16, false><<<512, 256, 0, stream>>>(hb, w2T, ffn_b2, x1, ln2_w, ln2_b, nullptr, x2b, DFF_);
    // out = x2 @ dec_w + dec_b  [8192,162] fp32, TM=32 -> 512 blocks
    gemm_bf16<EP_DEC, 32, 1><<<dim3(2, 256), 256, 0, stream>>>(x2b, dwT, dec_b, out, nullptr, M_, D_, D_);
}

// Round 9
// 217.328 us; speedup vs baseline: 1.0154x; 1.0154x over previous
//
#include <hip/hip_runtime.h>
#include <math.h>

#define T_    1024
#define B_    8
#define D_    256
#define H_    16
#define HD_   16
#define DFF_  2048
#define NODES_ 81
#define INDIM_ 162
#define E_    648
#define M_    (T_*B_)   // 8192 rows (t*B+b)

typedef __bf16 bf16x8 __attribute__((ext_vector_type(8)));
typedef float  f32x4  __attribute__((ext_vector_type(4)));
typedef unsigned short ushort_t;
typedef unsigned int   uint_t;

union bfpack { bf16x8 v; uint_t u[4]; };

__device__ __forceinline__ ushort_t f2bf(float f) {
    union { float f; uint_t u; } c; c.f = f;
    uint_t u = c.u;
    uint_t r = u + 0x7fffu + ((u >> 16) & 1u);
    return (ushort_t)(r >> 16);
}

__device__ __forceinline__ uint_t fbits(float f) {
    union { float f; uint_t u; } c; c.f = f;
    return c.u;
}

__device__ __forceinline__ bf16x8 zero8() {
    bf16x8 v;
#pragma unroll
    for (int e = 0; e < 8; e++) v[e] = (__bf16)0.0f;
    return v;
}

__device__ __forceinline__ void gload_lds16(const void* g, void* l) {
    __builtin_amdgcn_global_load_lds(
        (const __attribute__((address_space(1))) void*)g,
        (__attribute__((address_space(3))) void*)l, 16, 0, 0);
}

// ---------------------------------------------------------------------------
// One prep kernel: GCN-fold (A_hat in LDS) | 7 weight transposes | qkv bias |
// src->bf16 (batched, coalesced). Branch on blockIdx.x (block-uniform).
// grid 1555 x 256.
// ---------------------------------------------------------------------------
__device__ __forceinline__ void trans_tile(
        const float* __restrict__ in, ushort_t* __restrict__ out,
        float (*tile)[33], int K, int N, int Kp, int bx, int by) {
    int k0 = bx * 32, n0 = by * 32;
    int tx = threadIdx.x & 31, ty = threadIdx.x >> 5;
#pragma unroll
    for (int i = 0; i < 4; i++) {
        int r = k0 + ty + i * 8, c = n0 + tx;
        tile[ty + i * 8][tx] = (r < K && c < N) ? in[(size_t)r * N + c] : 0.f;
    }
    __syncthreads();
#pragma unroll
    for (int i = 0; i < 4; i++) {
        int r = n0 + ty + i * 8, c = k0 + tx;
        out[(size_t)r * Kp + c] = f2bf(tile[tx][ty + i * 8]);
    }
}

__global__ __launch_bounds__(256) void prep_all(
        const int* __restrict__ edge, const float* __restrict__ gcn_w,
        const float* __restrict__ gcn_b, const float* __restrict__ fc_w,
        const float* __restrict__ fc_b, const float* __restrict__ src,
        const float* __restrict__ wq, const float* __restrict__ wk,
        const float* __restrict__ wv, const float* __restrict__ wo,
        const float* __restrict__ dec_w, const float* __restrict__ w1,
        const float* __restrict__ w2,
        const float* __restrict__ bq, const float* __restrict__ bk,
        const float* __restrict__ bv,
        ushort_t* __restrict__ weffT, float* __restrict__ beff,
        ushort_t* __restrict__ srcb,
        ushort_t* __restrict__ wqkvT, ushort_t* __restrict__ woT,
        ushort_t* __restrict__ dwT, ushort_t* __restrict__ w1T,
        ushort_t* __restrict__ w2T, float* __restrict__ qkvbias) {
    __shared__ float A[NODES_ * NODES_];
    __shared__ float dinv[NODES_];
    __shared__ float tile[32][33];
    int bid = blockIdx.x;
    int tid = threadIdx.x;
    if (bid < 82) {
        for (int i = tid; i < NODES_ * NODES_; i += 256) A[i] = 0.f;
        __syncthreads();
        for (int e = tid; e < E_; e += 256) {
            int r = edge[e];
            int c = edge[E_ + e];
            atomicAdd(&A[c * NODES_ + r], 1.0f);
        }
        __syncthreads();
        if (tid < NODES_) A[tid * NODES_ + tid] += 1.0f;
        __syncthreads();
        if (tid < NODES_) {
            float s = 0.f;
            for (int k = 0; k < NODES_; k++) s += A[tid * NODES_ + k];
            dinv[tid] = (s > 0.f) ? rsqrtf(s) : 0.f;
        }
        __syncthreads();
        int d = tid, j = bid;
        if (j < NODES_) {
            float s0 = 0.f, s1 = 0.f;
            for (int i = 0; i < NODES_; i++) {
                float a = dinv[i] * A[i * NODES_ + j] * dinv[j];
                s0 += a * fc_w[(0 * NODES_ + i) * D_ + d];
                s1 += a * fc_w[(1 * NODES_ + i) * D_ + d];
            }
            weffT[d * 192 + j]          = f2bf(gcn_w[0] * s0 + gcn_w[1] * s1);
            weffT[d * 192 + NODES_ + j] = f2bf(gcn_w[2] * s0 + gcn_w[3] * s1);
        } else {
            float t0 = 0.f, t1 = 0.f;
            for (int i = 0; i < NODES_; i++) {
                t0 += fc_w[(0 * NODES_ + i) * D_ + d];
                t1 += fc_w[(1 * NODES_ + i) * D_ + d];
            }
            beff[d] = fc_b[d] + gcn_b[0] * t0 + gcn_b[1] * t1;
            for (int c = INDIM_; c < 192; c++) weffT[d * 192 + c] = 0;
        }
    } else if (bid < 1426) {
        int l = bid - 82;
        if (l < 64)        trans_tile(wq,    wqkvT,          tile, D_,   D_,     D_,   l & 7,  l >> 3);
        else if (l < 128)  trans_tile(wk,    wqkvT + 65536,  tile, D_,   D_,     D_,   (l-64) & 7,  (l-64) >> 3);
        else if (l < 192)  trans_tile(wv,    wqkvT + 131072, tile, D_,   D_,     D_,   (l-128) & 7, (l-128) >> 3);
        else if (l < 256)  trans_tile(wo,    woT,            tile, D_,   D_,     D_,   (l-192) & 7, (l-192) >> 3);
        else if (l < 320)  trans_tile(dec_w, dwT,            tile, D_,   INDIM_, D_,   (l-256) & 7, (l-256) >> 3);
        else if (l < 832)  trans_tile(w1,    w1T,            tile, D_,   DFF_,   D_,   (l-320) & 7, (l-320) >> 3);
        else               trans_tile(w2,    w2T,            tile, DFF_, D_,     DFF_, (l-832) & 63, (l-832) >> 6);
    } else if (bid == 1426) {
#pragma unroll
        for (int k = 0; k < 3; k++) {
            int i = k * 256 + tid;
            qkvbias[i] = (i < 256) ? bq[i] : ((i < 512) ? bk[i - 256] : bv[i - 512]);
        }
    } else {
        // src -> bf16 (padded to 192 cols): 128 blocks x 64 rows, coalesced.
        int blk = bid - 1427;               // 0..127
        size_t row0 = (size_t)blk * 64;
        const float* sp = src + row0 * INDIM_;
        ushort_t* dp = srcb + row0 * 192;
        for (int i = tid; i < 64 * INDIM_; i += 256) {
            int r = i / INDIM_;
            int c = i - r * INDIM_;
            dp[(size_t)r * 192 + c] = f2bf(sp[i]);
        }
        for (int i = tid; i < 64 * 30; i += 256) {
            int r = i / 30;
            int c = i - r * 30;
            dp[(size_t)r * 192 + INDIM_ + c] = 0;
        }
    }
}

// ---------------------------------------------------------------------------
// bf16 MFMA GEMM: C[M,N] = A[M,K] @ BT[N,K]^T + bias.
// TM=128: 128x128 tile, 4 waves x 64x64.  TM=64: 64x128, 4 waves x 64x32.
// TM=32: 32x128, 4 waves x 32x32 (grid doubles -> more blocks/CU, short-K).
// KS: split-K factor (EP_PART writes fp32 partial slabs, no bias).
// EP_QKV scales the q third by 0.25 (1/sqrt(HD), exact in bf16).
// ---------------------------------------------------------------------------
enum { EP_PE = 0, EP_QKV = 1, EP_PLAIN = 2, EP_RELU = 3, EP_DEC = 4, EP_PART = 5 };

template <int EPI, int TM, int KS>
__global__ __launch_bounds__(256) void gemm_bf16(
        const ushort_t* __restrict__ A, const ushort_t* __restrict__ BT,
        const float* __restrict__ bias, float* __restrict__ Cf,
        ushort_t* __restrict__ Cb, int M, int N, int K) {
    __shared__ ushort_t sA[TM * 64];
    __shared__ ushort_t sB[128 * 64];
    int tid = threadIdx.x;
    int w = tid >> 6, lane = tid & 63;
    int cc = lane & 15, q = lane >> 4;
    int bm = blockIdx.y * TM, bn = blockIdx.x * 128;
    int part = (KS > 1) ? blockIdx.z : 0;
    int kbeg = part * (K / KS), kend = kbeg + K / KS;

    int srow = (lane >> 3);
    int sslot = lane & 7;

    const int NI = (TM == 128) ? 4 : (TM / 16);
    const int NJ = (TM == 128) ? 4 : 2;
    int mbase = (TM == 128) ? ((w >> 1) * 64) : 0;
    int nbase = (TM == 128) ? ((w & 1) * 64) : (w * 32);

    f32x4 acc[NI][NJ];
#pragma unroll
    for (int i = 0; i < NI; i++)
#pragma unroll
        for (int j = 0; j < NJ; j++)
#pragma unroll
            for (int e = 0; e < 4; e++) acc[i][j][e] = 0.f;

    for (int k0 = kbeg; k0 < kend; k0 += 64) {
        if (TM == 128) {
#pragma unroll
            for (int i = 0; i < 4; i++) {
                int r = w * 32 + i * 8 + srow;
                const ushort_t* ga = A + (size_t)(bm + r) * K + k0 + ((sslot ^ (r & 7)) * 8);
                gload_lds16(ga, &sA[(w * 32 + i * 8) * 64]);
            }
        } else if (TM == 64) {
#pragma unroll
            for (int i = 0; i < 2; i++) {
                int r = w * 16 + i * 8 + srow;
                const ushort_t* ga = A + (size_t)(bm + r) * K + k0 + ((sslot ^ (r & 7)) * 8);
                gload_lds16(ga, &sA[(w * 16 + i * 8) * 64]);
            }
        } else {   // TM == 32
            int r = w * 8 + srow;
            const ushort_t* ga = A + (size_t)(bm + r) * K + k0 + ((sslot ^ (r & 7)) * 8);
            gload_lds16(ga, &sA[(w * 8) * 64]);
        }
#pragma unroll
        for (int i = 0; i < 4; i++) {
            int r = w * 32 + i * 8 + srow;
            const ushort_t* gb = BT + (size_t)(bn + r) * K + k0 + ((sslot ^ (r & 7)) * 8);
            gload_lds16(gb, &sB[(w * 32 + i * 8) * 64]);
        }
        __syncthreads();
#pragma unroll
        for (int ks = 0; ks < 2; ks++) {
            bf16x8 af[NI], bfr[NJ];
#pragma unroll
            for (int i = 0; i < NI; i++) {
                int m = mbase + i * 16 + cc;
                int off = m * 64 + (((ks * 4 + q) ^ (cc & 7)) * 8);
                af[i] = *(const bf16x8*)&sA[off];
            }
#pragma unroll
            for (int j = 0; j < NJ; j++) {
                int n = nbase + j * 16 + cc;
                int off = n * 64 + (((ks * 4 + q) ^ (cc & 7)) * 8);
                bfr[j] = *(const bf16x8*)&sB[off];
            }
#pragma unroll
            for (int i = 0; i < NI; i++)
#pragma unroll
                for (int j = 0; j < NJ; j++)
                    acc[i][j] = __builtin_amdgcn_mfma_f32_16x16x32_bf16(af[i], bfr[j], acc[i][j], 0, 0, 0);
        }
        __syncthreads();
    }

#pragma unroll
    for (int i = 0; i < NI; i++) {
#pragma unroll
        for (int j = 0; j < NJ; j++) {
            int col = bn + nbase + j * 16 + cc;
            float bv = 0.f;
            if (EPI == EP_DEC) bv = (col < INDIM_) ? bias[col] : 0.f;
            else if (EPI != EP_PART) bv = bias[col];
#pragma unroll
            for (int reg = 0; reg < 4; reg++) {
                int row = bm + mbase + i * 16 + q * 4 + reg;
                float v = acc[i][j][reg] + bv;
                if (EPI == EP_PE) {
                    int t = row >> 3;
                    float freq = __expf((float)(col & ~1) * (-9.210340371976184f / 256.f));
                    float ang = (float)t * freq;
                    v += (col & 1) ? __cosf(ang) : __sinf(ang);
                    Cf[(size_t)row * N + col] = v;
                    Cb[(size_t)row * N + col] = f2bf(v);
                } else if (EPI == EP_QKV) {
                    int t = row >> 3, b = row & 7;
                    int nn = col & 255, which = col >> 8;
                    int h = nn >> 4, hd = nn & 15;
                    float vq = (which == 0) ? v * 0.25f : v;   // fold 1/sqrt(HD) into q (exact)
                    Cb[(size_t)which * 2097152 +
                       ((size_t)((b * H_ + h) * T_ + t)) * HD_ + hd] = f2bf(vq);
                } else if (EPI == EP_PLAIN) {
                    Cf[(size_t)row * N + col] = v;
                } else if (EPI == EP_RELU) {
                    v = fmaxf(v, 0.f);
                    Cb[(size_t)row * N + col] = f2bf(v);
                } else if (EPI == EP_DEC) {
                    if (col < INDIM_) Cf[(size_t)row * INDIM_ + col] = v;
                } else if (EPI == EP_PART) {
                    Cf[(size_t)part * M * N + (size_t)row * N + col] = v;
                }
            }
        }
    }
}

// ---------------------------------------------------------------------------
// Fused GEMM + residual + LayerNorm (full row in one block, TN=256).
//   out = LN( X[row,:] + A[row,:]@BT^T + bias )  row-wise over 256 cols.
// 4 waves, wave w owns cols [w*64, w*64+64). TM=16 -> grid M/16=512 (2/CU).
// Only profitable at K=256 (LN1); K=2048 instance regressed (R8) — serial-K
// barrier chain beats the split-K+ln pair only when the K loop is short.
// ---------------------------------------------------------------------------
template <int TM, bool WF32>
__global__ __launch_bounds__(256) void gemm_ln(
        const ushort_t* __restrict__ A, const ushort_t* __restrict__ BT,
        const float* __restrict__ bias, const float* __restrict__ X,
        const float* __restrict__ lw, const float* __restrict__ lb,
        float* __restrict__ outF, ushort_t* __restrict__ outB, int K) {
    const int NI = TM / 16;
    __shared__ ushort_t sA[TM * 64];
    __shared__ ushort_t sB[256 * 64];
    __shared__ float red[4][TM][2];
    int tid = threadIdx.x;
    int w = tid >> 6, lane = tid & 63;
    int cc = lane & 15, q = lane >> 4;
    int bm = blockIdx.x * TM;
    int srow = lane >> 3, sslot = lane & 7;
    int nbase = w * 64;

    f32x4 acc[NI][4];
#pragma unroll
    for (int i = 0; i < NI; i++)
#pragma unroll
        for (int j = 0; j < 4; j++)
#pragma unroll
            for (int e = 0; e < 4; e++) acc[i][j][e] = 0.f;

    for (int k0 = 0; k0 < K; k0 += 64) {
        // stage A: TM rows x 64 k
        if (TM == 64) {
#pragma unroll
            for (int i = 0; i < 2; i++) {
                int r = w * 16 + i * 8 + srow;
                const ushort_t* ga = A + (size_t)(bm + r) * K + k0 + ((sslot ^ (r & 7)) * 8);
                gload_lds16(ga, &sA[(w * 16 + i * 8) * 64]);
            }
        } else if (TM == 32) {
            int r = w * 8 + srow;
            const ushort_t* ga = A + (size_t)(bm + r) * K + k0 + ((sslot ^ (r & 7)) * 8);
            gload_lds16(ga, &sA[(w * 8) * 64]);
        } else {   // TM == 16: waves 0,1 stage 8 rows each
            if (w < 2) {
                int r = w * 8 + srow;
                const ushort_t* ga = A + (size_t)(bm + r) * K + k0 + ((sslot ^ (r & 7)) * 8);
                gload_lds16(ga, &sA[(w * 8) * 64]);
            }
        }
        // stage B: all 256 n-rows x 64 k
#pragma unroll
        for (int i = 0; i < 8; i++) {
            int r = w * 64 + i * 8 + srow;
            const ushort_t* gb = BT + (size_t)r * K + k0 + ((sslot ^ (r & 7)) * 8);
            gload_lds16(gb, &sB[(w * 64 + i * 8) * 64]);
        }
        __syncthreads();
#pragma unroll
        for (int ks = 0; ks < 2; ks++) {
            bf16x8 af[NI], bfr[4];
#pragma unroll
            for (int i = 0; i < NI; i++) {
                int m = i * 16 + cc;
                int off = m * 64 + (((ks * 4 + q) ^ (cc & 7)) * 8);
                af[i] = *(const bf16x8*)&sA[off];
            }
#pragma unroll
            for (int j = 0; j < 4; j++) {
                int n = nbase + j * 16 + cc;
                int off = n * 64 + (((ks * 4 + q) ^ (cc & 7)) * 8);
                bfr[j] = *(const bf16x8*)&sB[off];
            }
#pragma unroll
            for (int i = 0; i < NI; i++)
#pragma unroll
                for (int j = 0; j < 4; j++)
                    acc[i][j] = __builtin_amdgcn_mfma_f32_16x16x32_bf16(af[i], bfr[j], acc[i][j], 0, 0, 0);
        }
        __syncthreads();
    }

    // epilogue: v = acc + bias + residual; row-wise LN over 256 cols
    float s[NI][4], sq[NI][4];
#pragma unroll
    for (int i = 0; i < NI; i++)
#pragma unroll
        for (int reg = 0; reg < 4; reg++) { s[i][reg] = 0.f; sq[i][reg] = 0.f; }

#pragma unroll
    for (int i = 0; i < NI; i++)
#pragma unroll
        for (int j = 0; j < 4; j++) {
            int col = nbase + j * 16 + cc;
            float bv = bias[col];
#pragma unroll
            for (int reg = 0; reg < 4; reg++) {
                int row = bm + i * 16 + q * 4 + reg;
                float v = acc[i][j][reg] + bv + X[(size_t)row * D_ + col];
                acc[i][j][reg] = v;
                s[i][reg] += v;
                sq[i][reg] += v * v;
            }
        }
    // reduce across the 16 cc-lanes (same q => same rows)
#pragma unroll
    for (int i = 0; i < NI; i++)
#pragma unroll
        for (int reg = 0; reg < 4; reg++) {
            float a = s[i][reg], b2 = sq[i][reg];
#pragma unroll
            for (int off = 1; off < 16; off <<= 1) {
                a += __shfl_xor(a, off);
                b2 += __shfl_xor(b2, off);
            }
            s[i][reg] = a; sq[i][reg] = b2;
        }
    if (cc == 0) {
#pragma unroll
        for (int i = 0; i < NI; i++)
#pragma unroll
            for (int reg = 0; reg < 4; reg++) {
                int lr = i * 16 + q * 4 + reg;
                red[w][lr][0] = s[i][reg];
                red[w][lr][1] = sq[i][reg];
            }
    }
    __syncthreads();
#pragma unroll
    for (int i = 0; i < NI; i++)
#pragma unroll
        for (int reg = 0; reg < 4; reg++) {
            int lr = i * 16 + q * 4 + reg;
            float ts = red[0][lr][0] + red[1][lr][0] + red[2][lr][0] + red[3][lr][0];
            float tq = red[0][lr][1] + red[1][lr][1] + red[2][lr][1] + red[3][lr][1];
            float mean = ts * (1.f / 256.f);
            float var  = tq * (1.f / 256.f) - mean * mean;
            float rstd = rsqrtf(var + 1e-5f);
            int row = bm + lr;
#pragma unroll
            for (int j = 0; j < 4; j++) {
                int col = nbase + j * 16 + cc;
                float o = (acc[i][j][reg] - mean) * rstd * lw[col] + lb[col];
                if (WF32) outF[(size_t)row * D_ + col] = o;
                outB[(size_t)row * D_ + col] = f2bf(o);
            }
        }
}

// ---------------------------------------------------------------------------
// MFMA causal attention v7: UNSPLIT — one block per (qc,bh) does its full
// causal key range and writes normalized bf16 ctx directly (no partials, no
// reduce kernel). Long blocks (qc=7, 16 kb) dispatch first via qc=7-blockIdx.y.
// PV packed across j-subtile pairs (full K=32); l via per-lane VALU + shfl
// butterfly (xor 16,32 gives every lane the full row sum).
// ---------------------------------------------------------------------------
__global__ __launch_bounds__(256) void attn_mfma(
        const ushort_t* __restrict__ Qb, const ushort_t* __restrict__ Kb,
        const ushort_t* __restrict__ Vb, ushort_t* __restrict__ ctxb) {
    int bh = blockIdx.x;
    int qc = 7 - blockIdx.y;       // longest blocks first
    int tid = threadIdx.x;
    int w = tid >> 6, lane = tid & 63;
    int cc = lane & 15, q = lane >> 4;
    int qb0 = qc * 128;
    int kend = 2 * (qc + 1);

    __shared__ ushort_t VTs[2][16 * 72];   // [hd][key], stride 72

    const ushort_t* Qp = Qb + (size_t)bh * (T_ * HD_);
    const ushort_t* Kp = Kb + (size_t)bh * (T_ * HD_);
    const ushort_t* Vp = Vb + (size_t)bh * (T_ * HD_);

    // Q fragments (B-operand): B[n=qrow][k=q*8+e], valid k<16 -> q<2
    bf16x8 qf[2];
#pragma unroll
    for (int i = 0; i < 2; i++) {
        if (q < 2)
            qf[i] = *(const bf16x8*)&Qp[(size_t)(qb0 + w * 32 + i * 16 + cc) * HD_ + q * 8];
        else
            qf[i] = zero8();
    }

    f32x4 ot[2];
    float lsum[2];
#pragma unroll
    for (int i = 0; i < 2; i++) {
        lsum[i] = 0.f;
#pragma unroll
        for (int e = 0; e < 4; e++) ot[i][e] = 0.f;
    }

    int qmaxw = qb0 + w * 32 + 31;

    for (int kb = 0; kb < kend; kb++) {
        ushort_t* vbuf = VTs[kb & 1];
        {   // V^T staging across all 256 threads (4 b16 writes each)
            int r = tid >> 2, c0 = (tid & 3) * 4;
            ushort4 vv = *(const ushort4*)&Vp[(size_t)(kb * 64 + r) * HD_ + c0];
            vbuf[(c0 + 0) * 72 + r] = vv.x;
            vbuf[(c0 + 1) * 72 + r] = vv.y;
            vbuf[(c0 + 2) * 72 + r] = vv.z;
            vbuf[(c0 + 3) * 72 + r] = vv.w;
        }
        __syncthreads();
        if (kb * 64 > qmaxw) continue;

        // hoisted K fragments: 4 independent global loads
        bf16x8 kf[4];
#pragma unroll
        for (int j = 0; j < 4; j++) {
            if (q < 2)
                kf[j] = *(const bf16x8*)&Kp[(size_t)(kb * 64 + j * 16 + cc) * HD_ + q * 8];
            else
                kf[j] = zero8();
        }

        // S^T = K.Q^T (q pre-scaled)
        f32x4 s[2][4];
#pragma unroll
        for (int j = 0; j < 4; j++)
#pragma unroll
            for (int i = 0; i < 2; i++) {
                f32x4 z;
#pragma unroll
                for (int e = 0; e < 4; e++) z[e] = 0.f;
                s[i][j] = __builtin_amdgcn_mfma_f32_16x16x32_bf16(kf[j], qf[i], z, 0, 0, 0);
            }

        // exp + (diagonal-only) mask + pack pairs -> single full-K PV MFMA
#pragma unroll
        for (int jj = 0; jj < 2; jj++) {
            int j0 = jj * 2, j1 = j0 + 1;
            bfpack af;
            const uint_t* vt0 = (const uint_t*)&vbuf[cc * 72 + j0 * 16 + q * 4];
            const uint_t* vt1 = (const uint_t*)&vbuf[cc * 72 + j1 * 16 + q * 4];
            af.u[0] = vt0[0]; af.u[1] = vt0[1];
            af.u[2] = vt1[0]; af.u[3] = vt1[1];
            int key00 = kb * 64 + j0 * 16 + q * 4;
            int key01 = key00 + 16;
#pragma unroll
            for (int i = 0; i < 2; i++) {
                float p0 = __expf(s[i][j0][0]);
                float p1 = __expf(s[i][j0][1]);
                float p2 = __expf(s[i][j0][2]);
                float p3 = __expf(s[i][j0][3]);
                float p4 = __expf(s[i][j1][0]);
                float p5 = __expf(s[i][j1][1]);
                float p6 = __expf(s[i][j1][2]);
                float p7 = __expf(s[i][j1][3]);
                int qsub = qb0 + w * 32 + i * 16;
                if (kb * 64 + j0 * 16 + 15 > qsub) {  // wave-uniform
                    int qrow = qsub + cc;
                    if (key00 + 0 > qrow) p0 = 0.f;
                    if (key00 + 1 > qrow) p1 = 0.f;
                    if (key00 + 2 > qrow) p2 = 0.f;
                    if (key00 + 3 > qrow) p3 = 0.f;
                }
                if (kb * 64 + j1 * 16 + 15 > qsub) {  // wave-uniform
                    int qrow = qsub + cc;
                    if (key01 + 0 > qrow) p4 = 0.f;
                    if (key01 + 1 > qrow) p5 = 0.f;
                    if (key01 + 2 > qrow) p6 = 0.f;
                    if (key01 + 3 > qrow) p7 = 0.f;
                }
                bfpack pf;
                pf.u[0] = (fbits(p0) >> 16) | (fbits(p1) & 0xffff0000u);
                pf.u[1] = (fbits(p2) >> 16) | (fbits(p3) & 0xffff0000u);
                pf.u[2] = (fbits(p4) >> 16) | (fbits(p5) & 0xffff0000u);
                pf.u[3] = (fbits(p6) >> 16) | (fbits(p7) & 0xffff0000u);
                ot[i] = __builtin_amdgcn_mfma_f32_16x16x32_bf16(af.v, pf.v, ot[i], 0, 0, 0);
                lsum[i] += ((p0 + p1) + (p2 + p3)) + ((p4 + p5) + (p6 + p7));
            }
        }
    }

    // epilogue: lane (cc,q) holds O^T d=q*4+reg for qrow=...+cc. The xor(16)+
    // xor(32) butterfly leaves the FULL row-sum l in every lane of the
    // cc-group, so each lane normalizes its own 4 outputs and writes bf16 ctx
    // directly: ctx[t*B+b, h*16 + q*4 .. +3].
    int b = bh >> 4, h = bh & 15;
#pragma unroll
    for (int i = 0; i < 2; i++) {
        float l = lsum[i];
        l += __shfl_xor(l, 16);
        l += __shfl_xor(l, 32);
        float inv = 1.f / l;
        int t = qb0 + w * 32 + i * 16 + cc;
        ushort4 u;
        u.x = f2bf(ot[i][0] * inv);
        u.y = f2bf(ot[i][1] * inv);
        u.z = f2bf(ot[i][2] * inv);
        u.w = f2bf(ot[i][3] * inv);
        *(ushort4*)&ctxb[((size_t)t * B_ + b) * D_ + h * HD_ + q * 4] = u;
    }
}

// ---------------------------------------------------------------------------
// Fused residual + (partial-sum) + LayerNorm. NP partial slabs, optional bias.
// WF32: whether the fp32 output slab is written (ln2's fp32 out is unused).
// ---------------------------------------------------------------------------
template <int NP, bool HASB, bool WF32>
__global__ __launch_bounds__(256) void ln_kernel(
        const float* __restrict__ X, const float* __restrict__ P0,
        const float* __restrict__ P1, const float* __restrict__ RB,
        const float* __restrict__ w, const float* __restrict__ b,
        float* __restrict__ out, ushort_t* __restrict__ outb) {
    int wv = threadIdx.x >> 6, lane = threadIdx.x & 63;
    int row = blockIdx.x * 4 + wv;
    int c = lane * 4;
    const float4 x4 = *(const float4*)&X[(size_t)row * D_ + c];
    const float4 p4 = *(const float4*)&P0[(size_t)row * D_ + c];
    float v0 = x4.x + p4.x, v1 = x4.y + p4.y, v2 = x4.z + p4.z, v3 = x4.w + p4.w;
    if (NP == 2) {
        const float4 q4 = *(const float4*)&P1[(size_t)row * D_ + c];
        v0 += q4.x; v1 += q4.y; v2 += q4.z; v3 += q4.w;
    }
    if (HASB) {
        const float4 r4 = *(const float4*)&RB[c];
        v0 += r4.x; v1 += r4.y; v2 += r4.z; v3 += r4.w;
    }
    float s  = v0 + v1 + v2 + v3;
    float sq = v0 * v0 + v1 * v1 + v2 * v2 + v3 * v3;
    for (int off = 32; off; off >>= 1) {
        s  += __shfl_xor(s, off);
        sq += __shfl_xor(sq, off);
    }
    float mean = s * (1.f / 256.f);
    float var  = sq * (1.f / 256.f) - mean * mean;
    float rstd = rsqrtf(var + 1e-5f);
    float o0 = (v0 - mean) * rstd * w[c + 0] + b[c + 0];
    float o1 = (v1 - mean) * rstd * w[c + 1] + b[c + 1];
    float o2 = (v2 - mean) * rstd * w[c + 2] + b[c + 2];
    float o3 = (v3 - mean) * rstd * w[c + 3] + b[c + 3];
    if (WF32) {
        float4 o; o.x = o0; o.y = o1; o.z = o2; o.w = o3;
        *(float4*)&out[(size_t)row * D_ + c] = o;
    }
    ushort4 ob;
    ob.x = f2bf(o0); ob.y = f2bf(o1); ob.z = f2bf(o2); ob.w = f2bf(o3);
    *(ushort4*)&outb[(size_t)row * D_ + c] = ob;
}

// ---------------------------------------------------------------------------
extern "C" void kernel_launch(void* const* d_in, const int* in_sizes, int n_in,
                              void* d_out, int out_size, void* d_ws, size_t ws_size,
                              hipStream_t stream) {
    (void)in_sizes; (void)n_in; (void)out_size; (void)ws_size;
    const float* src     = (const float*)d_in[0];
    const int*   edge    = (const int*)d_in[1];
    const float* gcn_w   = (const float*)d_in[2];
    const float* gcn_b   = (const float*)d_in[3];
    const float* fc_w    = (const float*)d_in[4];
    const float* fc_b    = (const float*)d_in[5];
    const float* wq      = (const float*)d_in[6];
    const float* bq      = (const float*)d_in[7];
    const float* wk      = (const float*)d_in[8];
    const float* bk      = (const float*)d_in[9];
    const float* wv      = (const float*)d_in[10];
    const float* bv      = (const float*)d_in[11];
    const float* wo      = (const float*)d_in[12];
    const float* bo      = (const float*)d_in[13];
    const float* ln1_w   = (const float*)d_in[14];
    const float* ln1_b   = (const float*)d_in[15];
    const float* ffn_w1  = (const float*)d_in[16];
    const float* ffn_b1  = (const float*)d_in[17];
    const float* ffn_w2  = (const float*)d_in[18];
    const float* ffn_b2  = (const float*)d_in[19];
    const float* ln2_w   = (const float*)d_in[20];
    const float* ln2_b   = (const float*)d_in[21];
    const float* dec_w   = (const float*)d_in[22];
    const float* dec_b   = (const float*)d_in[23];
    float* out = (float*)d_out;

    float* ws = (float*)d_ws;
    // fp32 region
    float* beff    = ws;                      // 256
    float* qkvbias = ws + 256;                // 768
    float* x0      = ws + 1024;               // 2097152
    float* tmp     = x0  + 2097152;           // 2 slabs (split-K partials)
    float* tmp2    = tmp + 2097152;
    float* x1      = tmp2 + 2097152;
    // bf16 region (float offset 10486784 -> 16B aligned)
    ushort_t* ub   = (ushort_t*)(ws + 10486784);
    ushort_t* srcb = ub;                      // 8192*192
    ushort_t* x0b  = ub + 1572864;            // 8192*256
    ushort_t* x1b  = x0b + 2097152;
    ushort_t* x2b  = x1b + 2097152;
    ushort_t* ctxb = x2b + 2097152;
    ushort_t* hb   = ctxb + 2097152;          // 8192*2048
    ushort_t* qkvb = hb + 16777216;           // 3 * 2097152
    ushort_t* weffT= qkvb + 6291456;          // 256*192
    ushort_t* wqkvT= weffT + 49152;           // 768*256
    ushort_t* woT  = wqkvT + 196608;          // 256*256
    ushort_t* w1T  = woT + 65536;             // 2048*256
    ushort_t* w2T  = w1T + 524288;            // 256*2048
    ushort_t* dwT  = w2T + 524288;            // 256*256 (rows 162..255 zero)

    prep_all<<<1555, 256, 0, stream>>>(edge, gcn_w, gcn_b, fc_w, fc_b, src,
                                       wq, wk, wv, wo, dec_w, ffn_w1, ffn_w2,
                                       bq, bk, bv, weffT, beff, srcb,
                                       wqkvT, woT, dwT, w1T, w2T, qkvbias);

    // x0 = src @ W_eff + b_eff + PE   (fp32 + bf16), TM=32 -> 512 blocks
    gemm_bf16<EP_PE, 32, 1><<<dim3(2, 256), 256, 0, stream>>>(srcb, weffT, beff, x0, x0b, M_, D_, 192);
    // fused q|k|v -> bf16 [B*H,T,16] x3 (q pre-scaled by 0.25), TM=32 -> 1536 blocks
    gemm_bf16<EP_QKV, 32, 1><<<dim3(6, 256), 256, 0, stream>>>(x0b, wqkvT, qkvbias, nullptr, qkvb, M_, 768, D_);
    // causal attention: unsplit, writes ctx bf16 [8192,256] directly
    attn_mfma<<<dim3(128, 8), 256, 0, stream>>>(qkvb, qkvb + 2097152, qkvb + 4194304, ctxb);
    // x1 = LN(x0 + ctx @ wo + bo)   fused GEMM+LN, TM=16 -> 512 blocks (2/CU)
    gemm_ln<16, true><<<512, 256, 0, stream>>>(ctxb, woT, bo, x0, ln1_w, ln1_b, x1, x1b, D_);
    // h = relu(x1 @ w1 + b1)  (bf16), TM=64 -> 2048 blocks
    gemm_bf16<EP_RELU, 64, 1><<<dim3(16, 128), 256, 0, stream>>>(x1b, w1T, ffn_b1, nullptr, hb, M_, DFF_, D_);
    // tmp/tmp2 = split-K partials of h @ w2, TM=32 -> 1024 blocks
    gemm_bf16<EP_PART, 32, 2><<<dim3(2, 256, 2), 256, 0, stream>>>(hb, w2T, nullptr, tmp, nullptr, M_, D_, DFF_);
    // x2 = LN(x1 + tmp + tmp2 + b2)  (bf16 out only; fp32 slab unused)
    ln_kernel<2, true, false><<<2048, 256, 0, stream>>>(x1, tmp, tmp2, ffn_b2, ln2_w, ln2_b, nullptr, x2b);
    // out = x2 @ dec_w + dec_b  [8192,162] fp32, TM=32 -> 512 blocks
    gemm_bf16<EP_DEC, 32, 1><<<dim3(2, 256), 256, 0, stream>>>(x2b, dwT, dec_b, out, nullptr, M_, D_, D_);
}